// Round 18
// baseline (153.384 us; speedup 1.0000x reference)
//
#include <hip/hip_runtime.h>
#include <math.h>

#define NH 4
#define NF 64
#define NM 32
#define NT 16  // nodes per block in k_projm
#define SC 32  // elements per thread in k_scan (supports N <= 32768)
#define AW 8   // waves per block in k_aggout

typedef __attribute__((ext_vector_type(8))) short bf16x8;
typedef __attribute__((ext_vector_type(4))) float f32x4;

__device__ __forceinline__ float softplusf(float v){ return fmaxf(v, 0.f) + log1pf(expf(-fabsf(v))); }
__device__ __forceinline__ float sigmoidf_(float v){ return 1.f / (1.f + expf(-v)); }
__device__ __forceinline__ unsigned short f2bf(float f) {
  unsigned u = __float_as_uint(f);
  u = u + 0x7FFFu + ((u >> 16) & 1u);   // round-to-nearest-even
  return (unsigned short)(u >> 16);
}
__device__ __forceinline__ float bflo(unsigned u){ return __uint_as_float(u << 16); }
__device__ __forceinline__ float bfhi(unsigned u){ return __uint_as_float(u & 0xFFFF0000u); }

// ---------------- K0: zero deg + cursor ----------------
__global__ void k_zero(int* __restrict__ z, int n) {
  int i = blockIdx.x * blockDim.x + threadIdx.x;
  if (i < n) z[i] = 0;
}

// ---------------- K0b: degree count ----------------
__global__ void k_count(const int* __restrict__ ei, int* __restrict__ deg, int E) {
  int e = blockIdx.x * blockDim.x + threadIdx.x;
  if (e < E) atomicAdd(&deg[ei[E + e]], 1);
}

// ---------------- K0c: pack weights into MFMA B-fragment order (bf16) ----------------
__global__ void k_pack(const float* __restrict__ Wp, const float* __restrict__ Wr,
                       const float* __restrict__ Wt,
                       const float* __restrict__ dW1, const float* __restrict__ tW1,
                       unsigned short* __restrict__ Wpk) {
  int t = blockIdx.x * blockDim.x + threadIdx.x;   // 8192 threads
  int lane = t & 63;
  int frag = t >> 6;   // 0..127
  if (frag >= 128) return;
  if (frag < 96) {
    int nb = frag & 3, kb = (frag >> 2) & 1, h = (frag >> 3) & 3, q = frag >> 5;
    const float* W = (q == 0 ? Wp : (q == 1 ? Wr : Wt));
    int col = nb * 16 + (lane & 15);
    int krow = kb * 32 + (lane >> 4) * 8;
    #pragma unroll
    for (int j = 0; j < 8; ++j)
      Wpk[((size_t)frag * 64 + lane) * 8 + j] = f2bf(W[(size_t)h * NF * NF + (krow + j) * NF + col]);
  } else {
    int f2 = frag - 96;
    int nb = f2 & 1, kb = (f2 >> 1) & 1, h = (f2 >> 2) & 3, p2 = f2 >> 4;
    const float* W = (p2 == 0 ? dW1 : tW1);
    int col = nb * 16 + (lane & 15);
    int krow = kb * 32 + (lane >> 4) * 8;
    #pragma unroll
    for (int j = 0; j < 8; ++j)
      Wpk[((size_t)frag * 64 + lane) * 8 + j] = f2bf(W[(size_t)h * NF * NM + (krow + j) * NM + col]);
  }
}

// ---------------- K1: MFMA node pass (pt stored bf16) ----------------
__global__ __launch_bounds__(256)
void k_projm(const float* __restrict__ x, const unsigned short* __restrict__ Wpk,
             const float* __restrict__ rsc, const float* __restrict__ tsc,
             const float* __restrict__ db1, const float* __restrict__ dw2, const float* __restrict__ db2,
             const float* __restrict__ tb1, const float* __restrict__ tw2, const float* __restrict__ tb2,
             const float* __restrict__ rdls, const float* __restrict__ rtb,
             unsigned short* __restrict__ ptb, float* __restrict__ sr, float* __restrict__ st,
             float* __restrict__ doff, float* __restrict__ toff, int N) {
  int n0 = blockIdx.x * NT;
  int tid = threadIdx.x;
  int h = tid >> 6, l = tid & 63;
  int lo = l & 15, hi = l >> 4;
  __shared__ __align__(16) unsigned short eps16[NH][16][72];  // bf16 ep, padded rows (144B)

  const bf16x8* W8 = (const bf16x8*)Wpk;

  // A fragments from x: lane l = row (n0+lo), k = kb*32 + hi*8 + j
  bf16x8 a[2];
  {
    int nr = n0 + lo; if (nr >= N) nr = N - 1;
    const float* xr = x + (size_t)nr * NF + hi * 8;
    #pragma unroll
    for (int kb = 0; kb < 2; ++kb) {
      float4 v0 = *(const float4*)(xr + kb * 32);
      float4 v1 = *(const float4*)(xr + kb * 32 + 4);
      bf16x8 aa;
      aa[0] = (short)f2bf(v0.x); aa[1] = (short)f2bf(v0.y);
      aa[2] = (short)f2bf(v0.z); aa[3] = (short)f2bf(v0.w);
      aa[4] = (short)f2bf(v1.x); aa[5] = (short)f2bf(v1.y);
      aa[6] = (short)f2bf(v1.z); aa[7] = (short)f2bf(v1.w);
      a[kb] = aa;
    }
  }

  float srp[4] = {0.f,0.f,0.f,0.f}, stp[4] = {0.f,0.f,0.f,0.f};
  // ---- projection GEMMs ----
  #pragma unroll
  for (int q = 0; q < 3; ++q) {
    #pragma unroll
    for (int nb = 0; nb < 4; ++nb) {
      f32x4 c = {0.f, 0.f, 0.f, 0.f};
      #pragma unroll
      for (int kb = 0; kb < 2; ++kb) {
        int frag = ((q * 4 + h) * 2 + kb) * 4 + nb;
        c = __builtin_amdgcn_mfma_f32_16x16x32_bf16(a[kb], W8[frag * 64 + l], c, 0, 0, 0);
      }
      int g = nb * 16 + lo;
      if (q == 0) {
        float rs = rsc[h * NF + g], ts = tsc[h * NF + g];
        #pragma unroll
        for (int r = 0; r < 4; ++r) {
          eps16[h][hi * 4 + r][g] = f2bf(c[r]);
          srp[r] += c[r] * rs;
          stp[r] += c[r] * ts;
        }
      } else {
        int row = (q - 1) * NH + h;
        #pragma unroll
        for (int r = 0; r < 4; ++r) {
          int n = n0 + hi * 4 + r;
          if (n < N) ptb[((size_t)n * NF + g) * 8 + row] = f2bf(c[r]);
        }
      }
    }
  }
  // reduce sr/st over the 16-lane column group
  #pragma unroll
  for (int off = 1; off < 16; off <<= 1)
    #pragma unroll
    for (int r = 0; r < 4; ++r) { srp[r] += __shfl_xor(srp[r], off); stp[r] += __shfl_xor(stp[r], off); }
  if (lo == 0) {
    #pragma unroll
    for (int r = 0; r < 4; ++r) {
      int n = n0 + hi * 4 + r;
      if (n < N) { sr[n * NH + h] = srp[r]; st[n * NH + h] = stp[r]; }
    }
  }

  // ---- MLPs (A = ep bf16 from wave-local LDS) ----
  asm volatile("s_waitcnt lgkmcnt(0)" ::: "memory");
  bf16x8 ea[2];
  #pragma unroll
  for (int kb = 0; kb < 2; ++kb)
    ea[kb] = *(const bf16x8*)&eps16[h][lo][kb * 32 + hi * 8];

  float dpp[4] = {0.f,0.f,0.f,0.f}, tpp[4] = {0.f,0.f,0.f,0.f};
  #pragma unroll
  for (int p2 = 0; p2 < 2; ++p2) {
    #pragma unroll
    for (int nb = 0; nb < 2; ++nb) {
      f32x4 c = {0.f, 0.f, 0.f, 0.f};
      #pragma unroll
      for (int kb = 0; kb < 2; ++kb) {
        int frag = 96 + ((p2 * 4 + h) * 2 + kb) * 2 + nb;
        c = __builtin_amdgcn_mfma_f32_16x16x32_bf16(ea[kb], W8[frag * 64 + l], c, 0, 0, 0);
      }
      int m = nb * 16 + lo;
      float b1 = (p2 == 0 ? db1 : tb1)[h * NM + m];
      float w2 = (p2 == 0 ? dw2 : tw2)[h * NM + m];
      #pragma unroll
      for (int r = 0; r < 4; ++r) {
        float av = c[r] + b1;
        float sv = av * sigmoidf_(av) * w2;   // silu * w2
        if (p2 == 0) dpp[r] += sv; else tpp[r] += sv;
      }
    }
  }
  #pragma unroll
  for (int off = 1; off < 16; off <<= 1)
    #pragma unroll
    for (int r = 0; r < 4; ++r) { dpp[r] += __shfl_xor(dpp[r], off); tpp[r] += __shfl_xor(tpp[r], off); }
  if (lo == 0) {
    float dbase = db2[h] + softplusf(rdls[h]);
    float tbase = tb2[h] + rtb[h];
    #pragma unroll
    for (int r = 0; r < 4; ++r) {
      int n = n0 + hi * 4 + r;
      if (n < N) { doff[n * NH + h] = dpp[r] + dbase; toff[n * NH + h] = tpp[r] + tbase; }
    }
  }
}

// ---------------- K2: exclusive prefix scan (thread-serial + one tree) ----------------
__global__ void k_scan(const int* __restrict__ deg, int* __restrict__ start, int N) {
  __shared__ int sums[1024];
  int tid = threadIdx.x;
  int base = tid * SC;
  int local[SC];
  int s = 0;
  #pragma unroll
  for (int j = 0; j < SC; ++j) {
    int i = base + j;
    int v = (i < N) ? deg[i] : 0;
    local[j] = s;   // exclusive local prefix
    s += v;
  }
  sums[tid] = s;
  __syncthreads();
  for (int off = 1; off < 1024; off <<= 1) {
    int t = (tid >= off) ? sums[tid - off] : 0;
    __syncthreads();
    sums[tid] += t;
    __syncthreads();
  }
  int tbase = (tid > 0) ? sums[tid - 1] : 0;
  #pragma unroll
  for (int j = 0; j < SC; ++j) {
    int i = base + j;
    if (i < N) start[i] = tbase + local[j];
  }
  if (tid == 1023) start[N] = sums[1023];
}

// ---------------- K3: per-edge logits + gate, written in CSR order ----------------
__global__ void k_edge(const int* __restrict__ ei, const float* __restrict__ elen,
                       const float4* __restrict__ sr4, const float4* __restrict__ st4,
                       const float4* __restrict__ doff4, const float4* __restrict__ toff4,
                       const float* __restrict__ rtw,
                       const float* __restrict__ mixb, const float* __restrict__ mixs,
                       const int* __restrict__ start, int* __restrict__ cursor,
                       float4* __restrict__ crl, float4* __restrict__ ctl, float4* __restrict__ cgv,
                       int* __restrict__ snd, int E) {
  int e = blockIdx.x * blockDim.x + threadIdx.x;
  if (e >= E) return;
  int s = ei[e], r = ei[E + e];
  float len = elen[e];
  int slot = start[r] + atomicAdd(&cursor[r], 1);
  float4 a = sr4[s], b = sr4[r], c = st4[s], d = st4[r], dof = doff4[r], tof = toff4[r];
  const float* ap = (const float*)&a; const float* bp = (const float*)&b;
  const float* cp = (const float*)&c; const float* dp = (const float*)&d;
  const float* dofp = (const float*)&dof; const float* tofp = (const float*)&tof;
  float rlv[NH], tlv[NH], gv[NH];
  #pragma unroll
  for (int h = 0; h < NH; ++h) {
    float temp = softplusf(tofp[h] + rtw[h] * len);
    rlv[h] = (ap[h] - bp[h] - dofp[h] * len) / (temp + 1e-4f);
    tlv[h] = cp[h] - dp[h];
    gv[h] = sigmoidf_(mixb[h] + mixs[h] * len);
  }
  crl[slot] = make_float4(rlv[0], rlv[1], rlv[2], rlv[3]);
  ctl[slot] = make_float4(tlv[0], tlv[1], tlv[2], tlv[3]);
  cgv[slot] = make_float4(gv[0], gv[1], gv[2], gv[3]);
  snd[slot] = s;
}

// ---------------- K4: per-receiver softmax + gather-aggregate + Wout + residual ----------------
__device__ __forceinline__ float dot8(const float* cf, uint4 uv) {
  return cf[0] * bflo(uv.x) + cf[1] * bfhi(uv.x)
       + cf[2] * bflo(uv.y) + cf[3] * bfhi(uv.y)
       + cf[4] * bflo(uv.z) + cf[5] * bfhi(uv.z)
       + cf[6] * bflo(uv.w) + cf[7] * bfhi(uv.w);
}

__global__ __launch_bounds__(512)
void k_aggout(const int* __restrict__ start, const int* __restrict__ snd,
              const float4* __restrict__ crl, const float4* __restrict__ ctl, const float4* __restrict__ cgv,
              const unsigned short* __restrict__ ptb, const float* __restrict__ x,
              const float* __restrict__ Wout, float* __restrict__ out, int N) {
  __shared__ float wout_s[NF * NF];
  __shared__ float coef_s[AW][64][8];
  __shared__ int   snd_s[AW][64];
  __shared__ float am_s[AW][NF];
  int tid = threadIdx.x;
  {
    const float4* w4 = (const float4*)Wout;
    float4* s4 = (float4*)wout_s;
    for (int i = tid; i < NF * NF / 4; i += 512) s4[i] = w4[i];
  }
  __syncthreads();   // only block-wide barrier; everything after is wave-local
  int w = tid >> 6, g = tid & 63;
  int n = blockIdx.x * AW + w;
  if (n >= N) return;
  int i0 = start[n], i1 = start[n + 1];

  // pass A: per-head max (edge-parallel, lane = edge)
  float rm[NH] = {-1e30f, -1e30f, -1e30f, -1e30f};
  float tm[NH] = {-1e30f, -1e30f, -1e30f, -1e30f};
  for (int i = i0 + g; i < i1; i += 64) {
    float4 rv = crl[i], tv = ctl[i];
    const float* rp_ = (const float*)&rv; const float* tp_ = (const float*)&tv;
    #pragma unroll
    for (int h = 0; h < NH; ++h) { rm[h] = fmaxf(rm[h], rp_[h]); tm[h] = fmaxf(tm[h], tp_[h]); }
  }
  #pragma unroll
  for (int off = 32; off; off >>= 1)
    #pragma unroll
    for (int h = 0; h < NH; ++h) {
      rm[h] = fmaxf(rm[h], __shfl_xor(rm[h], off));
      tm[h] = fmaxf(tm[h], __shfl_xor(tm[h], off));
    }

  // pass B: per-head exp-sum
  float rs_[NH] = {0.f, 0.f, 0.f, 0.f}, ts_[NH] = {0.f, 0.f, 0.f, 0.f};
  for (int i = i0 + g; i < i1; i += 64) {
    float4 rv = crl[i], tv = ctl[i];
    const float* rp_ = (const float*)&rv; const float* tp_ = (const float*)&tv;
    #pragma unroll
    for (int h = 0; h < NH; ++h) { rs_[h] += expf(rp_[h] - rm[h]); ts_[h] += expf(tp_[h] - tm[h]); }
  }
  #pragma unroll
  for (int off = 32; off; off >>= 1)
    #pragma unroll
    for (int h = 0; h < NH; ++h) { rs_[h] += __shfl_xor(rs_[h], off); ts_[h] += __shfl_xor(ts_[h], off); }
  #pragma unroll
  for (int h = 0; h < NH; ++h) { rs_[h] = 1.f / (rs_[h] + 1e-9f); ts_[h] = 1.f / (ts_[h] + 1e-9f); }

  // pass C: coefficients (lane=edge) + gather-aggregate (lane=feature, bf16 pt, 4-way ILP)
  float acc0 = 0.f, acc1 = 0.f, acc2 = 0.f, acc3 = 0.f;
  float sc1[NH] = {0.f, 0.f, 0.f, 0.f}, sc2[NH] = {0.f, 0.f, 0.f, 0.f};
  for (int base = i0; base < i1; base += 64) {
    int i = base + g;
    if (i < i1) {
      float4 rv = crl[i], tv = ctl[i], gv = cgv[i];
      const float* rp_ = (const float*)&rv; const float* tp_ = (const float*)&tv;
      const float* gp_ = (const float*)&gv;
      #pragma unroll
      for (int h = 0; h < NH; ++h) {
        float ar = expf(rp_[h] - rm[h]) * rs_[h];
        float at = expf(tp_[h] - tm[h]) * ts_[h];
        float gg = gp_[h];
        float ba = gg * ar + (1.f - gg) * at;
        float c1 = ba * gg, c2 = ba * (1.f - gg);
        coef_s[w][g][h] = c1; coef_s[w][g][4 + h] = c2;
        sc1[h] += c1; sc2[h] += c2;
      }
      snd_s[w][g] = snd[i];
    }
    int cnt = min(64, i1 - base);
    int j = 0;
    for (; j + 4 <= cnt; j += 4) {
      uint4 u0 = *(const uint4*)(ptb + ((size_t)snd_s[w][j]     * NF + g) * 8);
      uint4 u1 = *(const uint4*)(ptb + ((size_t)snd_s[w][j + 1] * NF + g) * 8);
      uint4 u2 = *(const uint4*)(ptb + ((size_t)snd_s[w][j + 2] * NF + g) * 8);
      uint4 u3 = *(const uint4*)(ptb + ((size_t)snd_s[w][j + 3] * NF + g) * 8);
      acc0 += dot8(coef_s[w][j],     u0);
      acc1 += dot8(coef_s[w][j + 1], u1);
      acc2 += dot8(coef_s[w][j + 2], u2);
      acc3 += dot8(coef_s[w][j + 3], u3);
    }
    for (; j < cnt; ++j) {
      uint4 u0 = *(const uint4*)(ptb + ((size_t)snd_s[w][j] * NF + g) * 8);
      acc0 += dot8(coef_s[w][j], u0);
    }
  }
  float acc = (acc0 + acc1) + (acc2 + acc3);
  // reduce coefficient sums across the wave (each lane held its own edges' share)
  #pragma unroll
  for (int off = 32; off; off >>= 1)
    #pragma unroll
    for (int h = 0; h < NH; ++h) { sc1[h] += __shfl_xor(sc1[h], off); sc2[h] += __shfl_xor(sc2[h], off); }

  {
    uint4 uv = *(const uint4*)(ptb + ((size_t)n * NF + g) * 8);
    acc -= sc1[0] * bflo(uv.x) + sc1[1] * bfhi(uv.x)
         + sc1[2] * bflo(uv.y) + sc1[3] * bfhi(uv.y)
         + sc2[0] * bflo(uv.z) + sc2[1] * bfhi(uv.z)
         + sc2[2] * bflo(uv.w) + sc2[3] * bfhi(uv.w);
  }
  acc *= (1.f / NH);

  am_s[w][g] = acc;   // wave-local LDS; no block barrier needed
  float o = x[(size_t)n * NF + g];
  #pragma unroll 8
  for (int f = 0; f < NF; ++f) o += am_s[w][f] * wout_s[f * NF + g];
  out[(size_t)n * NF + g] = o;
}

extern "C" void kernel_launch(void* const* d_in, const int* in_sizes, int n_in,
                              void* d_out, int out_size, void* d_ws, size_t ws_size,
                              hipStream_t stream) {
  const float* x    = (const float*)d_in[0];
  const int*   ei   = (const int*)d_in[1];
  // d_in[2] = edge_vec, unused by the reference
  const float* elen = (const float*)d_in[3];
  const float* Wp   = (const float*)d_in[4];
  const float* Wr   = (const float*)d_in[5];
  const float* Wt   = (const float*)d_in[6];
  const float* rsc  = (const float*)d_in[7];
  const float* tsc  = (const float*)d_in[8];
  const float* rdls = (const float*)d_in[9];
  const float* rtb  = (const float*)d_in[10];
  const float* rtw  = (const float*)d_in[11];
  const float* mixb = (const float*)d_in[12];
  const float* mixs = (const float*)d_in[13];
  const float* dW1  = (const float*)d_in[14];
  const float* db1  = (const float*)d_in[15];
  const float* dw2  = (const float*)d_in[16];
  const float* db2  = (const float*)d_in[17];
  const float* tW1  = (const float*)d_in[18];
  const float* tb1  = (const float*)d_in[19];
  const float* tw2  = (const float*)d_in[20];
  const float* tb2  = (const float*)d_in[21];
  const float* Wout = (const float*)d_in[22];

  int N = in_sizes[0] / NF;
  int E = in_sizes[3];

  float* p = (float*)d_ws;
  unsigned short* Wpk = (unsigned short*)p; p += 32768;  // 128 frag x 64 lanes x 8 bf16 = 131072 B
  unsigned short* ptb = (unsigned short*)p; p += (size_t)N * NF * 8 / 2;  // [n][g][8] bf16
  float* sr   = p; p += (size_t)N * NH;
  float* st   = p; p += (size_t)N * NH;
  float* doff = p; p += (size_t)N * NH;
  float* toff = p; p += (size_t)N * NH;
  float* crl  = p; p += (size_t)E * NH;       // CSR-ordered radial logits
  float* ctl  = p; p += (size_t)E * NH;       // CSR-ordered tangential logits
  float* cgv  = p; p += (size_t)E * NH;       // CSR-ordered mix gate
  int* snd    = (int*)p; p += E;              // CSR-ordered sender ids
  int* deg    = (int*)p; p += N;
  int* cursor = (int*)p; p += N;
  int* startp = (int*)p; p += N + 1;

  // K0: zero deg + cursor (contiguous)
  k_zero<<<(2 * N + 255) / 256, 256, 0, stream>>>(deg, 2 * N);
  // K0b: degree count
  k_count<<<(E + 255) / 256, 256, 0, stream>>>(ei, deg, E);
  // K0c: pack weights into MFMA fragments
  k_pack<<<32, 256, 0, stream>>>(Wp, Wr, Wt, dW1, tW1, Wpk);
  // K1: MFMA node pass
  k_projm<<<(N + NT - 1) / NT, 256, 0, stream>>>(x, Wpk, rsc, tsc, db1, dw2, db2,
                                                 tb1, tw2, tb2, rdls, rtb,
                                                 ptb, sr, st, doff, toff, N);
  // K2: scan degrees -> CSR starts
  k_scan<<<1, 1024, 0, stream>>>(deg, startp, N);
  // K3: per-edge logits into CSR slots
  k_edge<<<(E + 255) / 256, 256, 0, stream>>>(ei, elen, (const float4*)sr, (const float4*)st,
                                              (const float4*)doff, (const float4*)toff,
                                              rtw, mixb, mixs, startp, cursor,
                                              (float4*)crl, (float4*)ctl, (float4*)cgv, snd, E);
  // K4: softmax + aggregate + output
  k_aggout<<<(N + AW - 1) / AW, 512, 0, stream>>>(startp, snd, (const float4*)crl, (const float4*)ctl,
                                                  (const float4*)cgv, ptb, x, Wout, (float*)d_out, N);
}

// Round 19
// 147.764 us; speedup vs baseline: 1.0380x; 1.0380x over previous
//
#include <hip/hip_runtime.h>
#include <math.h>

#define NH 4
#define NF 64
#define NM 32
#define NT 16  // nodes per block in k_projm
#define SC 32  // elements per thread in k_scan (supports N <= 32768)
#define AW 8   // waves per block in k_aggout

typedef __attribute__((ext_vector_type(8))) short bf16x8;
typedef __attribute__((ext_vector_type(4))) float f32x4;

__device__ __forceinline__ float softplusf(float v){ return fmaxf(v, 0.f) + log1pf(expf(-fabsf(v))); }
__device__ __forceinline__ float sigmoidf_(float v){ return 1.f / (1.f + expf(-v)); }
__device__ __forceinline__ unsigned short f2bf(float f) {
  unsigned u = __float_as_uint(f);
  u = u + 0x7FFFu + ((u >> 16) & 1u);   // round-to-nearest-even
  return (unsigned short)(u >> 16);
}
__device__ __forceinline__ float bflo(unsigned u){ return __uint_as_float(u << 16); }
__device__ __forceinline__ float bfhi(unsigned u){ return __uint_as_float(u & 0xFFFF0000u); }

// ---------------- K0: zero deg + cursor ----------------
__global__ void k_zero(int* __restrict__ z, int n) {
  int i = blockIdx.x * blockDim.x + threadIdx.x;
  if (i < n) z[i] = 0;
}

// ---------------- K0b: degree count ----------------
__global__ void k_count(const int* __restrict__ ei, int* __restrict__ deg, int E) {
  int e = blockIdx.x * blockDim.x + threadIdx.x;
  if (e < E) atomicAdd(&deg[ei[E + e]], 1);
}

// ---------------- K0c: pack weights into MFMA B-fragment order (bf16) ----------------
__global__ void k_pack(const float* __restrict__ Wp, const float* __restrict__ Wr,
                       const float* __restrict__ Wt,
                       const float* __restrict__ dW1, const float* __restrict__ tW1,
                       unsigned short* __restrict__ Wpk) {
  int t = blockIdx.x * blockDim.x + threadIdx.x;   // 8192 threads
  int lane = t & 63;
  int frag = t >> 6;   // 0..127
  if (frag >= 128) return;
  if (frag < 96) {
    int nb = frag & 3, kb = (frag >> 2) & 1, h = (frag >> 3) & 3, q = frag >> 5;
    const float* W = (q == 0 ? Wp : (q == 1 ? Wr : Wt));
    int col = nb * 16 + (lane & 15);
    int krow = kb * 32 + (lane >> 4) * 8;
    #pragma unroll
    for (int j = 0; j < 8; ++j)
      Wpk[((size_t)frag * 64 + lane) * 8 + j] = f2bf(W[(size_t)h * NF * NF + (krow + j) * NF + col]);
  } else {
    int f2 = frag - 96;
    int nb = f2 & 1, kb = (f2 >> 1) & 1, h = (f2 >> 2) & 3, p2 = f2 >> 4;
    const float* W = (p2 == 0 ? dW1 : tW1);
    int col = nb * 16 + (lane & 15);
    int krow = kb * 32 + (lane >> 4) * 8;
    #pragma unroll
    for (int j = 0; j < 8; ++j)
      Wpk[((size_t)frag * 64 + lane) * 8 + j] = f2bf(W[(size_t)h * NF * NM + (krow + j) * NM + col]);
  }
}

// ---------------- K1: MFMA node pass (pt stored bf16) ----------------
__global__ __launch_bounds__(256)
void k_projm(const float* __restrict__ x, const unsigned short* __restrict__ Wpk,
             const float* __restrict__ rsc, const float* __restrict__ tsc,
             const float* __restrict__ db1, const float* __restrict__ dw2, const float* __restrict__ db2,
             const float* __restrict__ tb1, const float* __restrict__ tw2, const float* __restrict__ tb2,
             const float* __restrict__ rdls, const float* __restrict__ rtb,
             unsigned short* __restrict__ ptb, float* __restrict__ sr, float* __restrict__ st,
             float* __restrict__ doff, float* __restrict__ toff, int N) {
  int n0 = blockIdx.x * NT;
  int tid = threadIdx.x;
  int h = tid >> 6, l = tid & 63;
  int lo = l & 15, hi = l >> 4;
  __shared__ __align__(16) unsigned short eps16[NH][16][72];  // bf16 ep, padded rows (144B)

  const bf16x8* W8 = (const bf16x8*)Wpk;

  // A fragments from x: lane l = row (n0+lo), k = kb*32 + hi*8 + j
  bf16x8 a[2];
  {
    int nr = n0 + lo; if (nr >= N) nr = N - 1;
    const float* xr = x + (size_t)nr * NF + hi * 8;
    #pragma unroll
    for (int kb = 0; kb < 2; ++kb) {
      float4 v0 = *(const float4*)(xr + kb * 32);
      float4 v1 = *(const float4*)(xr + kb * 32 + 4);
      bf16x8 aa;
      aa[0] = (short)f2bf(v0.x); aa[1] = (short)f2bf(v0.y);
      aa[2] = (short)f2bf(v0.z); aa[3] = (short)f2bf(v0.w);
      aa[4] = (short)f2bf(v1.x); aa[5] = (short)f2bf(v1.y);
      aa[6] = (short)f2bf(v1.z); aa[7] = (short)f2bf(v1.w);
      a[kb] = aa;
    }
  }

  float srp[4] = {0.f,0.f,0.f,0.f}, stp[4] = {0.f,0.f,0.f,0.f};
  // ---- projection GEMMs ----
  #pragma unroll
  for (int q = 0; q < 3; ++q) {
    #pragma unroll
    for (int nb = 0; nb < 4; ++nb) {
      f32x4 c = {0.f, 0.f, 0.f, 0.f};
      #pragma unroll
      for (int kb = 0; kb < 2; ++kb) {
        int frag = ((q * 4 + h) * 2 + kb) * 4 + nb;
        c = __builtin_amdgcn_mfma_f32_16x16x32_bf16(a[kb], W8[frag * 64 + l], c, 0, 0, 0);
      }
      int g = nb * 16 + lo;
      if (q == 0) {
        float rs = rsc[h * NF + g], ts = tsc[h * NF + g];
        #pragma unroll
        for (int r = 0; r < 4; ++r) {
          eps16[h][hi * 4 + r][g] = f2bf(c[r]);
          srp[r] += c[r] * rs;
          stp[r] += c[r] * ts;
        }
      } else {
        int row = (q - 1) * NH + h;
        #pragma unroll
        for (int r = 0; r < 4; ++r) {
          int n = n0 + hi * 4 + r;
          if (n < N) ptb[((size_t)n * NF + g) * 8 + row] = f2bf(c[r]);
        }
      }
    }
  }
  // reduce sr/st over the 16-lane column group
  #pragma unroll
  for (int off = 1; off < 16; off <<= 1)
    #pragma unroll
    for (int r = 0; r < 4; ++r) { srp[r] += __shfl_xor(srp[r], off); stp[r] += __shfl_xor(stp[r], off); }
  if (lo == 0) {
    #pragma unroll
    for (int r = 0; r < 4; ++r) {
      int n = n0 + hi * 4 + r;
      if (n < N) { sr[n * NH + h] = srp[r]; st[n * NH + h] = stp[r]; }
    }
  }

  // ---- MLPs (A = ep bf16 from wave-local LDS) ----
  asm volatile("s_waitcnt lgkmcnt(0)" ::: "memory");
  bf16x8 ea[2];
  #pragma unroll
  for (int kb = 0; kb < 2; ++kb)
    ea[kb] = *(const bf16x8*)&eps16[h][lo][kb * 32 + hi * 8];

  float dpp[4] = {0.f,0.f,0.f,0.f}, tpp[4] = {0.f,0.f,0.f,0.f};
  #pragma unroll
  for (int p2 = 0; p2 < 2; ++p2) {
    #pragma unroll
    for (int nb = 0; nb < 2; ++nb) {
      f32x4 c = {0.f, 0.f, 0.f, 0.f};
      #pragma unroll
      for (int kb = 0; kb < 2; ++kb) {
        int frag = 96 + ((p2 * 4 + h) * 2 + kb) * 2 + nb;
        c = __builtin_amdgcn_mfma_f32_16x16x32_bf16(ea[kb], W8[frag * 64 + l], c, 0, 0, 0);
      }
      int m = nb * 16 + lo;
      float b1 = (p2 == 0 ? db1 : tb1)[h * NM + m];
      float w2 = (p2 == 0 ? dw2 : tw2)[h * NM + m];
      #pragma unroll
      for (int r = 0; r < 4; ++r) {
        float av = c[r] + b1;
        float sv = av * sigmoidf_(av) * w2;   // silu * w2
        if (p2 == 0) dpp[r] += sv; else tpp[r] += sv;
      }
    }
  }
  #pragma unroll
  for (int off = 1; off < 16; off <<= 1)
    #pragma unroll
    for (int r = 0; r < 4; ++r) { dpp[r] += __shfl_xor(dpp[r], off); tpp[r] += __shfl_xor(tpp[r], off); }
  if (lo == 0) {
    float dbase = db2[h] + softplusf(rdls[h]);
    float tbase = tb2[h] + rtb[h];
    #pragma unroll
    for (int r = 0; r < 4; ++r) {
      int n = n0 + hi * 4 + r;
      if (n < N) { doff[n * NH + h] = dpp[r] + dbase; toff[n * NH + h] = tpp[r] + tbase; }
    }
  }
}

// ---------------- K2: exclusive prefix scan (thread-serial + one tree) ----------------
__global__ void k_scan(const int* __restrict__ deg, int* __restrict__ start, int N) {
  __shared__ int sums[1024];
  int tid = threadIdx.x;
  int base = tid * SC;
  int local[SC];
  int s = 0;
  #pragma unroll
  for (int j = 0; j < SC; ++j) {
    int i = base + j;
    int v = (i < N) ? deg[i] : 0;
    local[j] = s;   // exclusive local prefix
    s += v;
  }
  sums[tid] = s;
  __syncthreads();
  for (int off = 1; off < 1024; off <<= 1) {
    int t = (tid >= off) ? sums[tid - off] : 0;
    __syncthreads();
    sums[tid] += t;
    __syncthreads();
  }
  int tbase = (tid > 0) ? sums[tid - 1] : 0;
  #pragma unroll
  for (int j = 0; j < SC; ++j) {
    int i = base + j;
    if (i < N) start[i] = tbase + local[j];
  }
  if (tid == 1023) start[N] = sums[1023];
}

// ---------------- K3: CSR fill (snd + elen only) ----------------
__global__ void k_fill(const int* __restrict__ ei, const float* __restrict__ elen,
                       const int* __restrict__ start, int* __restrict__ cursor,
                       int* __restrict__ csnd, float* __restrict__ celen, int E) {
  int e = blockIdx.x * blockDim.x + threadIdx.x;
  if (e >= E) return;
  int r = ei[E + e];
  int slot = start[r] + atomicAdd(&cursor[r], 1);
  csnd[slot] = ei[e];
  celen[slot] = elen[e];
}

// ---------------- K4: fused logits + softmax + gather-aggregate + Wout + residual ----------------
__device__ __forceinline__ float dot8(const float* cf, uint4 uv) {
  return cf[0] * bflo(uv.x) + cf[1] * bfhi(uv.x)
       + cf[2] * bflo(uv.y) + cf[3] * bfhi(uv.y)
       + cf[4] * bflo(uv.z) + cf[5] * bfhi(uv.z)
       + cf[6] * bflo(uv.w) + cf[7] * bfhi(uv.w);
}

__global__ __launch_bounds__(512)
void k_aggout(const int* __restrict__ start, const int* __restrict__ csnd, const float* __restrict__ celen,
              const float4* __restrict__ sr4, const float4* __restrict__ st4,
              const float4* __restrict__ doff4, const float4* __restrict__ toff4,
              const float* __restrict__ rtw, const float* __restrict__ mixb, const float* __restrict__ mixs,
              const unsigned short* __restrict__ ptb, const float* __restrict__ x,
              const float* __restrict__ Wout, float* __restrict__ out, int N) {
  __shared__ float wout_s[NF * NF];
  __shared__ float coef_s[AW][64][8];
  __shared__ int   snd_s[AW][64];
  __shared__ float am_s[AW][NF];
  int tid = threadIdx.x;
  {
    const float4* w4 = (const float4*)Wout;
    float4* s4 = (float4*)wout_s;
    for (int i = tid; i < NF * NF / 4; i += 512) s4[i] = w4[i];
  }
  __syncthreads();   // only block-wide barrier; everything after is wave-local
  int w = tid >> 6, g = tid & 63;
  int n = blockIdx.x * AW + w;
  if (n >= N) return;
  int i0 = start[n], i1 = start[n + 1];
  int deg = i1 - i0;

  // receiver-side broadcast values
  float4 srn = sr4[n], stn = st4[n], dofn = doff4[n], tofn = toff4[n];
  const float* srnp = (const float*)&srn; const float* stnp = (const float*)&stn;
  const float* dofnp = (const float*)&dofn; const float* tofnp = (const float*)&tofn;
  float rtwv[NH], mbv[NH], msv[NH];
  #pragma unroll
  for (int h = 0; h < NH; ++h) { rtwv[h] = rtw[h]; mbv[h] = mixb[h]; msv[h] = mixs[h]; }

  float rm[NH], tm[NH];
  float rs_[NH] = {0.f,0.f,0.f,0.f}, ts_[NH] = {0.f,0.f,0.f,0.f};
  float sc1[NH] = {0.f,0.f,0.f,0.f}, sc2[NH] = {0.f,0.f,0.f,0.f};
  float acc0 = 0.f, acc1 = 0.f, acc2 = 0.f, acc3 = 0.f;

  if (deg <= 64) {
    // ---------- fast path: lane = edge, logits live in registers ----------
    int i = i0 + g;
    bool act = (i < i1);
    int s = act ? csnd[i] : 0;
    float len = act ? celen[i] : 0.f;
    float4 as4 = sr4[s], cs4 = st4[s];
    const float* asp = (const float*)&as4; const float* csp = (const float*)&cs4;
    float rlv[NH], tlv[NH], gvv[NH];
    #pragma unroll
    for (int h = 0; h < NH; ++h) {
      float temp = softplusf(tofnp[h] + rtwv[h] * len);
      rlv[h] = act ? (asp[h] - srnp[h] - dofnp[h] * len) / (temp + 1e-4f) : -1e30f;
      tlv[h] = act ? (csp[h] - stnp[h]) : -1e30f;
      gvv[h] = sigmoidf_(mbv[h] + msv[h] * len);
      rm[h] = rlv[h]; tm[h] = tlv[h];
    }
    #pragma unroll
    for (int off = 32; off; off >>= 1)
      #pragma unroll
      for (int h = 0; h < NH; ++h) {
        rm[h] = fmaxf(rm[h], __shfl_xor(rm[h], off));
        tm[h] = fmaxf(tm[h], __shfl_xor(tm[h], off));
      }
    float er[NH], et[NH];
    #pragma unroll
    for (int h = 0; h < NH; ++h) {
      er[h] = act ? expf(rlv[h] - rm[h]) : 0.f;
      et[h] = act ? expf(tlv[h] - tm[h]) : 0.f;
      rs_[h] = er[h]; ts_[h] = et[h];
    }
    #pragma unroll
    for (int off = 32; off; off >>= 1)
      #pragma unroll
      for (int h = 0; h < NH; ++h) { rs_[h] += __shfl_xor(rs_[h], off); ts_[h] += __shfl_xor(ts_[h], off); }
    #pragma unroll
    for (int h = 0; h < NH; ++h) { rs_[h] = 1.f / (rs_[h] + 1e-9f); ts_[h] = 1.f / (ts_[h] + 1e-9f); }
    #pragma unroll
    for (int h = 0; h < NH; ++h) {
      float ar = er[h] * rs_[h];
      float at = et[h] * ts_[h];
      float gg = gvv[h];
      float ba = gg * ar + (1.f - gg) * at;
      float c1 = ba * gg, c2 = ba * (1.f - gg);
      coef_s[w][g][h] = c1; coef_s[w][g][4 + h] = c2;
      sc1[h] = c1; sc2[h] = c2;   // inactive lanes: er=et=0 -> c1=c2=0
    }
    snd_s[w][g] = s;
    // gather (lane = feature, 4-way ILP)
    int j = 0;
    for (; j + 4 <= deg; j += 4) {
      uint4 u0 = *(const uint4*)(ptb + ((size_t)snd_s[w][j]     * NF + g) * 8);
      uint4 u1 = *(const uint4*)(ptb + ((size_t)snd_s[w][j + 1] * NF + g) * 8);
      uint4 u2 = *(const uint4*)(ptb + ((size_t)snd_s[w][j + 2] * NF + g) * 8);
      uint4 u3 = *(const uint4*)(ptb + ((size_t)snd_s[w][j + 3] * NF + g) * 8);
      acc0 += dot8(coef_s[w][j],     u0);
      acc1 += dot8(coef_s[w][j + 1], u1);
      acc2 += dot8(coef_s[w][j + 2], u2);
      acc3 += dot8(coef_s[w][j + 3], u3);
    }
    for (; j < deg; ++j) {
      uint4 u0 = *(const uint4*)(ptb + ((size_t)snd_s[w][j] * NF + g) * 8);
      acc0 += dot8(coef_s[w][j], u0);
    }
  } else {
    // ---------- slow path (deg > 64): chunked 3 passes, logits recomputed ----------
    #pragma unroll
    for (int h = 0; h < NH; ++h) { rm[h] = -1e30f; tm[h] = -1e30f; }
    for (int base = i0; base < i1; base += 64) {
      int i = base + g; bool act = (i < i1);
      int s = act ? csnd[i] : 0; float len = act ? celen[i] : 0.f;
      float4 as4 = sr4[s], cs4 = st4[s];
      const float* asp = (const float*)&as4; const float* csp = (const float*)&cs4;
      #pragma unroll
      for (int h = 0; h < NH; ++h) {
        float temp = softplusf(tofnp[h] + rtwv[h] * len);
        float rl = act ? (asp[h] - srnp[h] - dofnp[h] * len) / (temp + 1e-4f) : -1e30f;
        float tl = act ? (csp[h] - stnp[h]) : -1e30f;
        rm[h] = fmaxf(rm[h], rl); tm[h] = fmaxf(tm[h], tl);
      }
    }
    #pragma unroll
    for (int off = 32; off; off >>= 1)
      #pragma unroll
      for (int h = 0; h < NH; ++h) {
        rm[h] = fmaxf(rm[h], __shfl_xor(rm[h], off));
        tm[h] = fmaxf(tm[h], __shfl_xor(tm[h], off));
      }
    for (int base = i0; base < i1; base += 64) {
      int i = base + g; bool act = (i < i1);
      int s = act ? csnd[i] : 0; float len = act ? celen[i] : 0.f;
      float4 as4 = sr4[s], cs4 = st4[s];
      const float* asp = (const float*)&as4; const float* csp = (const float*)&cs4;
      #pragma unroll
      for (int h = 0; h < NH; ++h) {
        float temp = softplusf(tofnp[h] + rtwv[h] * len);
        float rl = act ? (asp[h] - srnp[h] - dofnp[h] * len) / (temp + 1e-4f) : -1e30f;
        float tl = act ? (csp[h] - stnp[h]) : -1e30f;
        rs_[h] += act ? expf(rl - rm[h]) : 0.f;
        ts_[h] += act ? expf(tl - tm[h]) : 0.f;
      }
    }
    #pragma unroll
    for (int off = 32; off; off >>= 1)
      #pragma unroll
      for (int h = 0; h < NH; ++h) { rs_[h] += __shfl_xor(rs_[h], off); ts_[h] += __shfl_xor(ts_[h], off); }
    #pragma unroll
    for (int h = 0; h < NH; ++h) { rs_[h] = 1.f / (rs_[h] + 1e-9f); ts_[h] = 1.f / (ts_[h] + 1e-9f); }
    for (int base = i0; base < i1; base += 64) {
      int i = base + g; bool act = (i < i1);
      int s = act ? csnd[i] : 0; float len = act ? celen[i] : 0.f;
      float4 as4 = sr4[s], cs4 = st4[s];
      const float* asp = (const float*)&as4; const float* csp = (const float*)&cs4;
      #pragma unroll
      for (int h = 0; h < NH; ++h) {
        float temp = softplusf(tofnp[h] + rtwv[h] * len);
        float rl = act ? (asp[h] - srnp[h] - dofnp[h] * len) / (temp + 1e-4f) : -1e30f;
        float tl = act ? (csp[h] - stnp[h]) : -1e30f;
        float gg = sigmoidf_(mbv[h] + msv[h] * len);
        float ar = (act ? expf(rl - rm[h]) : 0.f) * rs_[h];
        float at = (act ? expf(tl - tm[h]) : 0.f) * ts_[h];
        float ba = gg * ar + (1.f - gg) * at;
        float c1 = ba * gg, c2 = ba * (1.f - gg);
        coef_s[w][g][h] = c1; coef_s[w][g][4 + h] = c2;
        sc1[h] += c1; sc2[h] += c2;
      }
      snd_s[w][g] = s;
      int cnt = min(64, i1 - base);
      int j = 0;
      for (; j + 4 <= cnt; j += 4) {
        uint4 u0 = *(const uint4*)(ptb + ((size_t)snd_s[w][j]     * NF + g) * 8);
        uint4 u1 = *(const uint4*)(ptb + ((size_t)snd_s[w][j + 1] * NF + g) * 8);
        uint4 u2 = *(const uint4*)(ptb + ((size_t)snd_s[w][j + 2] * NF + g) * 8);
        uint4 u3 = *(const uint4*)(ptb + ((size_t)snd_s[w][j + 3] * NF + g) * 8);
        acc0 += dot8(coef_s[w][j],     u0);
        acc1 += dot8(coef_s[w][j + 1], u1);
        acc2 += dot8(coef_s[w][j + 2], u2);
        acc3 += dot8(coef_s[w][j + 3], u3);
      }
      for (; j < cnt; ++j) {
        uint4 u0 = *(const uint4*)(ptb + ((size_t)snd_s[w][j] * NF + g) * 8);
        acc0 += dot8(coef_s[w][j], u0);
      }
    }
  }

  float acc = (acc0 + acc1) + (acc2 + acc3);
  // reduce coefficient sums across the wave (each lane held its own edges' share)
  #pragma unroll
  for (int off = 32; off; off >>= 1)
    #pragma unroll
    for (int h = 0; h < NH; ++h) { sc1[h] += __shfl_xor(sc1[h], off); sc2[h] += __shfl_xor(sc2[h], off); }

  {
    uint4 uv = *(const uint4*)(ptb + ((size_t)n * NF + g) * 8);
    acc -= sc1[0] * bflo(uv.x) + sc1[1] * bfhi(uv.x)
         + sc1[2] * bflo(uv.y) + sc1[3] * bfhi(uv.y)
         + sc2[0] * bflo(uv.z) + sc2[1] * bfhi(uv.z)
         + sc2[2] * bflo(uv.w) + sc2[3] * bfhi(uv.w);
  }
  acc *= (1.f / NH);

  am_s[w][g] = acc;   // wave-local LDS; no block barrier needed
  float o = x[(size_t)n * NF + g];
  #pragma unroll 8
  for (int f = 0; f < NF; ++f) o += am_s[w][f] * wout_s[f * NF + g];
  out[(size_t)n * NF + g] = o;
}

extern "C" void kernel_launch(void* const* d_in, const int* in_sizes, int n_in,
                              void* d_out, int out_size, void* d_ws, size_t ws_size,
                              hipStream_t stream) {
  const float* x    = (const float*)d_in[0];
  const int*   ei   = (const int*)d_in[1];
  // d_in[2] = edge_vec, unused by the reference
  const float* elen = (const float*)d_in[3];
  const float* Wp   = (const float*)d_in[4];
  const float* Wr   = (const float*)d_in[5];
  const float* Wt   = (const float*)d_in[6];
  const float* rsc  = (const float*)d_in[7];
  const float* tsc  = (const float*)d_in[8];
  const float* rdls = (const float*)d_in[9];
  const float* rtb  = (const float*)d_in[10];
  const float* rtw  = (const float*)d_in[11];
  const float* mixb = (const float*)d_in[12];
  const float* mixs = (const float*)d_in[13];
  const float* dW1  = (const float*)d_in[14];
  const float* db1  = (const float*)d_in[15];
  const float* dw2  = (const float*)d_in[16];
  const float* db2  = (const float*)d_in[17];
  const float* tW1  = (const float*)d_in[18];
  const float* tb1  = (const float*)d_in[19];
  const float* tw2  = (const float*)d_in[20];
  const float* tb2  = (const float*)d_in[21];
  const float* Wout = (const float*)d_in[22];

  int N = in_sizes[0] / NF;
  int E = in_sizes[3];

  float* p = (float*)d_ws;
  unsigned short* Wpk = (unsigned short*)p; p += 32768;  // 128 frag x 64 lanes x 8 bf16 = 131072 B
  unsigned short* ptb = (unsigned short*)p; p += (size_t)N * NF * 8 / 2;  // [n][g][8] bf16
  float* sr   = p; p += (size_t)N * NH;
  float* st   = p; p += (size_t)N * NH;
  float* doff = p; p += (size_t)N * NH;
  float* toff = p; p += (size_t)N * NH;
  int* csnd   = (int*)p; p += E;              // CSR-ordered sender ids
  float* celen = p; p += E;                   // CSR-ordered edge lengths
  int* deg    = (int*)p; p += N;
  int* cursor = (int*)p; p += N;
  int* startp = (int*)p; p += N + 1;

  // K0: zero deg + cursor (contiguous)
  k_zero<<<(2 * N + 255) / 256, 256, 0, stream>>>(deg, 2 * N);
  // K0b: degree count
  k_count<<<(E + 255) / 256, 256, 0, stream>>>(ei, deg, E);
  // K0c: pack weights into MFMA fragments
  k_pack<<<32, 256, 0, stream>>>(Wp, Wr, Wt, dW1, tW1, Wpk);
  // K1: MFMA node pass
  k_projm<<<(N + NT - 1) / NT, 256, 0, stream>>>(x, Wpk, rsc, tsc, db1, dw2, db2,
                                                 tb1, tw2, tb2, rdls, rtb,
                                                 ptb, sr, st, doff, toff, N);
  // K2: scan degrees -> CSR starts
  k_scan<<<1, 1024, 0, stream>>>(deg, startp, N);
  // K3: CSR fill (snd + elen)
  k_fill<<<(E + 255) / 256, 256, 0, stream>>>(ei, elen, startp, cursor, csnd, celen, E);
  // K4: fused logits + softmax + aggregate + output
  k_aggout<<<(N + AW - 1) / AW, 512, 0, stream>>>(startp, csnd, celen,
                                                  (const float4*)sr, (const float4*)st,
                                                  (const float4*)doff, (const float4*)toff,
                                                  rtw, mixb, mixs, ptb, x, Wout, (float*)d_out, N);
}